// Round 8
// baseline (174.248 us; speedup 1.0000x reference)
//
#include <hip/hip_runtime.h>

namespace {
constexpr int NA    = 5;
constexpr int NCELL = 361;            // 19*19
constexpr int NBOX  = 1805;           // NA * NCELL
constexpr int SORTN = 2048;
constexpr int NT1   = 256;            // K1: 8 elems/thread register bitonic
constexpr int TMAX  = 50;
constexpr float CONF_T = 0.5f;
constexpr float NMS_T  = 0.45f;
constexpr float IOU_T  = 0.5f;
constexpr int NW      = 29;           // max 64-bit words (ceil(1805/64))
constexpr int NWMAX   = 32;
constexpr int ROWPAD  = 1856;         // padded col dim (mult of 64, >= 1805)
constexpr int SOA_STRIDE = ROWPAD;
constexpr int SOA_ARR    = 8 * SOA_STRIDE;
// ws layout (bytes)
constexpr size_t WS_COUNT = 0;        // 4 ints: prop, corr, total, done
constexpr size_t WS_M     = 64;       // 8 ints
constexpr size_t WS_SOA   = 256;      // 6 * SOA_ARR floats = 356,352 B
constexpr size_t WS_SUP   = 360448;   // 8 * 32 * ROWPAD * 8 = 3,801,088 B
}

__device__ __constant__ float d_anchw[NA] = {1.3221f, 3.19275f, 5.05587f, 9.47112f, 11.2364f};
__device__ __constant__ float d_anchh[NA] = {1.73145f, 4.00944f, 8.09892f, 4.84053f, 10.0071f};

// uniform-index 64-bit readlane (constant idx after unroll): ~3 cyc
__device__ inline unsigned long long rdlane64(unsigned long long v, int l) {
    unsigned lo = (unsigned)__builtin_amdgcn_readlane((int)(unsigned)(v & 0xffffffffull), l);
    unsigned hi = (unsigned)__builtin_amdgcn_readlane((int)(unsigned)(v >> 32), l);
    return ((unsigned long long)hi << 32) | lo;
}

// ---- K1: decode + register-blocked bitonic sort + sorted SoA to global ----
__global__ __launch_bounds__(NT1, 1) void k_decode_sort(
    const float* __restrict__ net, float* __restrict__ soa,
    int* __restrict__ Marr, int* __restrict__ counters)
{
    __shared__ unsigned long long skey[SORTN];   // 16 KB
    __shared__ float4 sbox[NBOX];                // 28.9 KB
    __shared__ int sM;
    const int b = blockIdx.x, tid = threadIdx.x;
    const float* op = net + (size_t)b * (NA * 25 * NCELL);
    if (tid == 0) sM = 0;
    if (b == 0 && tid < 4) counters[tid] = 0;    // replaces memset dispatch

    for (int n = tid; n < NBOX; n += NT1) {
        int a = n / NCELL;
        int r = n - a * NCELL;
        int y = r / 19;
        int x = r - y * 19;
        int base = a * 25 * NCELL + r;
        float t0 = op[base];
        float t1 = op[base + 1 * NCELL];
        float t2 = op[base + 2 * NCELL];
        float t3 = op[base + 3 * NCELL];
        float t4 = op[base + 4 * NCELL];
        float cx = (1.0f / (1.0f + expf(-t0)) + (float)x) / 19.0f;
        float cy = (1.0f / (1.0f + expf(-t1)) + (float)y) / 19.0f;
        float bw = expf(t2) * (d_anchw[a] / 19.0f);
        float bh = expf(t3) * (d_anchh[a] / 19.0f);
        float det = 1.0f / (1.0f + expf(-t4));
        sbox[n] = make_float4(cx, cy, bw, bh);
        skey[n] = ((unsigned long long)(~__float_as_uint(det)) << 32) | (unsigned)n;
    }
    for (int n = NBOX + tid; n < SORTN; n += NT1) skey[n] = ~0ull;
    __syncthreads();

    unsigned long long v[8];
    const int base8 = tid << 3;
    auto cas = [&](int x, int y, bool up) {
        unsigned long long a = v[x], c = v[y];
        if ((a > c) == up) { v[x] = c; v[y] = a; }
    };
    {
        #pragma unroll
        for (int p = 0; p < 8; ++p) v[p] = skey[base8 + p];
        cas(0,1,true); cas(2,3,false); cas(4,5,true); cas(6,7,false);
        cas(0,2,true); cas(1,3,true); cas(4,6,false); cas(5,7,false);
        cas(0,1,true); cas(2,3,true); cas(4,5,false); cas(6,7,false);
        bool u8 = ((base8 & 8) == 0);
        cas(0,4,u8); cas(1,5,u8); cas(2,6,u8); cas(3,7,u8);
        cas(0,2,u8); cas(1,3,u8); cas(4,6,u8); cas(5,7,u8);
        cas(0,1,u8); cas(2,3,u8); cas(4,5,u8); cas(6,7,u8);
        #pragma unroll
        for (int p = 0; p < 8; ++p) skey[base8 + p] = v[p];
    }
    __syncthreads();
    for (unsigned k = 16; k <= SORTN; k <<= 1) {
        for (unsigned j = k >> 1; j >= 8; j >>= 1) {
            #pragma unroll
            for (int c = 0; c < 4; ++c) {
                unsigned m = (tid << 2) + c;
                unsigned i = ((m & ~(j - 1)) << 1) | (m & (j - 1));
                unsigned p = i | j;
                bool up = ((i & k) == 0);
                unsigned long long a = skey[i], c2 = skey[p];
                if ((a > c2) == up) { skey[i] = c2; skey[p] = a; }
            }
            __syncthreads();
        }
        {
            #pragma unroll
            for (int p = 0; p < 8; ++p) v[p] = skey[base8 + p];
            bool up = ((base8 & k) == 0);
            cas(0,4,up); cas(1,5,up); cas(2,6,up); cas(3,7,up);
            cas(0,2,up); cas(1,3,up); cas(4,6,up); cas(5,7,up);
            cas(0,1,up); cas(2,3,up); cas(4,5,up); cas(6,7,up);
            #pragma unroll
            for (int p = 0; p < 8; ++p) skey[base8 + p] = v[p];
        }
        __syncthreads();
    }

    float* X1 = soa + 0 * SOA_ARR + b * SOA_STRIDE;
    float* Y1 = soa + 1 * SOA_ARR + b * SOA_STRIDE;
    float* X2 = soa + 2 * SOA_ARR + b * SOA_STRIDE;
    float* Y2 = soa + 3 * SOA_ARR + b * SOA_STRIDE;
    float* Wd = soa + 4 * SOA_ARR + b * SOA_STRIDE;
    float* Hd = soa + 5 * SOA_ARR + b * SOA_STRIDE;
    for (int p = tid; p < NBOX; p += NT1) {
        unsigned long long kk = skey[p];
        int n = (int)(unsigned)(kk & 0xffffffffull);
        float det = __uint_as_float(~(unsigned)(kk >> 32));
        float4 bx = sbox[n];
        X1[p] = bx.x - 0.5f * bx.z;
        Y1[p] = bx.y - 0.5f * bx.w;
        X2[p] = bx.x + 0.5f * bx.z;
        Y2[p] = bx.y + 0.5f * bx.w;
        Wd[p] = bx.z;
        Hd[p] = bx.w;
        if (det > CONF_T) {
            float dn = 0.0f;
            if (p + 1 < NBOX) dn = __uint_as_float(~(unsigned)(skey[p + 1] >> 32));
            if (!(dn > CONF_T)) sM = p + 1;      // unique boundary thread
        }
    }
    __syncthreads();
    if (tid == 0) Marr[b] = sM;
}

// ---- K2: COLUMN-oriented suppression words. One wave per sorted col j;
// lanes = rows i. supC[b][t][j] = ballot over rows i in tile t of
// "i suppresses j" (i<j, iou>thresh). XCD-swizzled (b = blk&7). ----
__global__ __launch_bounds__(256) void k_iou_colT(
    const float* __restrict__ soa, const int* __restrict__ Marr,
    unsigned long long* __restrict__ supC)
{
    const int blk  = blockIdx.x;
    const int b    = blk & 7;
    const int lane = threadIdx.x & 63;
    const int j    = (blk >> 3) * 4 + (threadIdx.x >> 6);
    const int M = Marr[b];
    if (j >= M) return;
    const float* X1 = soa + 0 * SOA_ARR + b * SOA_STRIDE;
    const float* Y1 = soa + 1 * SOA_ARR + b * SOA_STRIDE;
    const float* X2 = soa + 2 * SOA_ARR + b * SOA_STRIDE;
    const float* Y2 = soa + 3 * SOA_ARR + b * SOA_STRIDE;
    const float* Wd = soa + 4 * SOA_ARR + b * SOA_STRIDE;
    const float* Hd = soa + 5 * SOA_ARR + b * SOA_STRIDE;
    // box j (wave-uniform)
    const float bx1 = X1[j], by1 = Y1[j], bx2 = X2[j], by2 = Y2[j];
    const float bw = Wd[j], bh = Hd[j], barea = bw * bh;
    const int jw = j >> 6;
    unsigned long long* outp = supC + (size_t)b * 32 * ROWPAD + j;
    for (int t = 0; t <= jw; ++t) {
        int i = (t << 6) + lane;                 // i <= 1855 < ROWPAD: in-bounds
        float ax1 = X1[i], ay1 = Y1[i], ax2 = X2[i], ay2 = Y2[i];
        float aw = Wd[i], ah = Hd[i];
        bool pred = false;
        if (i < j) {                             // i<j implies i<M
            float uw = fmaxf(ax2, bx2) - fminf(ax1, bx1);
            float uh = fmaxf(ay2, by2) - fminf(ay1, by1);
            float cw = aw + bw - uw;
            float ch = ah + bh - uh;
            if (cw > 0.0f && ch > 0.0f) {
                float ca = cw * ch;
                float ua = aw * ah + barea - ca;
                pred = ca > NMS_T * ua;          // iou > thresh
            }
        }
        unsigned long long m = __ballot(pred);
        if (lane == 0) outp[(size_t)t * ROWPAD] = m;
    }
}

// ---- K3: wave-0 barrier-free NMS (ballot gather + ballot sweep, keep masks
// in a lane-indexed register) + 8-wave GT match from LDS SoA. ----
__global__ __launch_bounds__(512, 1) void k_sweep(
    const float* __restrict__ soa, const float* __restrict__ tgt,
    const int* __restrict__ Marr, const unsigned long long* __restrict__ supC,
    int* __restrict__ counters, float* __restrict__ out)
{
    __shared__ float X1s[NBOX], Y1s[NBOX], X2s[NBOX], Y2s[NBOX];
    __shared__ float Wss[NBOX], Hss[NBOX];               // 43.3 KB
    __shared__ unsigned long long keepw[NWMAX];
    __shared__ int sNV, sCorr, sProp;
    const int b = blockIdx.x, tid = threadIdx.x;
    const int wv = tid >> 6, lane = tid & 63;
    const int M = Marr[b];
    const int nwa = (M + 63) >> 6;

    if (tid < NWMAX) keepw[tid] = 0ull;
    if (tid == 0) { sCorr = 0; sProp = 0; }

    // stage sorted SoA into LDS (coalesced, 8 waves)
    {
        const float* X1 = soa + 0 * SOA_ARR + b * SOA_STRIDE;
        const float* Y1 = soa + 1 * SOA_ARR + b * SOA_STRIDE;
        const float* X2 = soa + 2 * SOA_ARR + b * SOA_STRIDE;
        const float* Y2 = soa + 3 * SOA_ARR + b * SOA_STRIDE;
        const float* Wd = soa + 4 * SOA_ARR + b * SOA_STRIDE;
        const float* Hd = soa + 5 * SOA_ARR + b * SOA_STRIDE;
        for (int p = tid; p < NBOX; p += 512) {
            X1s[p] = X1[p]; Y1s[p] = Y1[p];
            X2s[p] = X2[p]; Y2s[p] = Y2[p];
            Wss[p] = Wd[p]; Hss[p] = Hd[p];
        }
    }
    if (wv == 1) {       // GT count via ballot (first row with cx==0)
        float cxv = (lane < TMAX) ? tgt[b * 250 + lane * 5 + 1] : 0.0f;
        unsigned long long bm = __ballot(cxv != 0.0f);
        unsigned long long inv = (~bm) & ((1ull << TMAX) - 1);
        if (lane == 0) sNV = inv ? (__ffsll((long long)inv) - 1) : TMAX;
    }
    __syncthreads();

    // ---- wave 0: full greedy NMS, no barriers, no memory on serial chain ----
    if (wv == 0 && nwa > 0) {
        const unsigned long long* sb = supC + (size_t)b * 32 * ROWPAD;
        unsigned long long kwv = 0;      // lane t holds keep-mask of tile t
        int pcTot = 0;
        for (int t = 0; t < nwa; ++t) {
            // gather: cols of word t suppressed by kept rows of earlier tiles.
            // 28 independent coalesced loads -> one wait -> 28 cheap ballots.
            unsigned long long cur = 0;
            #pragma unroll
            for (int tp = 0; tp < NW; ++tp) {
                if (tp < t) {
                    unsigned long long v = sb[(size_t)tp * ROWPAD + (t << 6) + lane];
                    unsigned long long kw = rdlane64(kwv, tp);   // const idx
                    cur |= __ballot((v & kw) != 0ull);
                }
            }
            // diag block (i<j already enforced in K2)
            unsigned long long colw = sb[(size_t)t * ROWPAD + (t << 6) + lane];
            int rem = M - (t << 6);
            unsigned long long vm = (rem >= 64) ? ~0ull : ((1ull << rem) - 1ull);
            unsigned long long removed = cur;
            unsigned long long live = vm & ~removed;
            while (live) {                       // ~kept-count iterations
                int i = __ffsll((long long)live) - 1;            // uniform
                unsigned long long w = __ballot(((colw >> i) & 1ull) != 0ull);
                removed |= w;
                live &= ~w;
                live &= ~(1ull << i);
            }
            unsigned long long kp = vm & ~removed;
            pcTot += __popcll(kp);
            kwv = (lane == t) ? kp : kwv;
        }
        if (lane < NWMAX) keepw[lane] = (lane < nwa) ? kwv : 0ull;
        if (lane == 0) sProp = pcTot;
    }
    __syncthreads();

    // ---- GT matching: 8 waves, branchless, LDS SoA ----
    const int nv = sNV;
    for (int t = wv; t < nv; t += 8) {
        const float* g = tgt + b * 250 + t * 5;
        float gcx = g[1], gcy = g[2], gw = g[3], gh = g[4];
        float gx1 = gcx - 0.5f * gw, gx2 = gcx + 0.5f * gw;
        float gy1 = gcy - 0.5f * gh, gy2 = gcy + 0.5f * gh;
        float garea = gw * gh;
        float best = 0.0f;
        for (int j0 = 0; j0 < M; j0 += 64) {
            int j = j0 + lane;
            bool ok = (j < M) && ((keepw[j0 >> 6] >> lane) & 1ull);
            int js = (j < NBOX) ? j : (NBOX - 1);
            float bw = Wss[js], bh = Hss[js];
            float uw = fmaxf(gx2, X2s[js]) - fminf(gx1, X1s[js]);
            float uh = fmaxf(gy2, Y2s[js]) - fminf(gy1, Y1s[js]);
            float cww = gw + bw - uw, chh = gh + bh - uh;
            float ca = (cww > 0.0f && chh > 0.0f) ? cww * chh : 0.0f;
            float ua = garea + bw * bh - ca;
            float iou = ca / ua;
            best = fmaxf(best, ok ? iou : 0.0f);
        }
        for (int d = 32; d > 0; d >>= 1) best = fmaxf(best, __shfl_down(best, d, 64));
        if (lane == 0 && best > IOU_T) atomicAdd(&sCorr, 1);
    }
    __syncthreads();

    if (tid == 0) {
        atomicAdd(counters + 0, sProp);
        atomicAdd(counters + 1, sCorr);
        atomicAdd(counters + 2, sNV);
        __threadfence();
        int done = atomicAdd(counters + 3, 1);
        if (done == 7) {
            float prop  = (float)atomicAdd(counters + 0, 0);
            float corr  = (float)atomicAdd(counters + 1, 0);
            float total = (float)atomicAdd(counters + 2, 0);
            float prec = corr / (prop + 1e-6f);
            float rec  = corr / (total + 1e-6f);
            float fs   = 2.0f * prec * rec / (prec + rec + 1e-6f);
            out[0] = total;
            out[1] = prop;
            out[2] = corr;
            out[3] = prec;
            out[4] = rec;
            out[5] = fs;
        }
    }
}

extern "C" void kernel_launch(void* const* d_in, const int* in_sizes, int n_in,
                              void* d_out, int out_size, void* d_ws, size_t ws_size,
                              hipStream_t stream) {
    const float* net = (const float*)d_in[0];   // [8,125,19,19] f32
    const float* tgt = (const float*)d_in[1];   // [8,250] f32
    char* ws = (char*)d_ws;
    int* counters = (int*)(ws + WS_COUNT);
    int* Marr     = (int*)(ws + WS_M);
    float* soa    = (float*)(ws + WS_SOA);
    unsigned long long* supC = (unsigned long long*)(ws + WS_SUP);

    k_decode_sort<<<8, NT1, 0, stream>>>(net, soa, Marr, counters);
    int colblocks = (NBOX + 3) / 4;              // 452
    k_iou_colT<<<colblocks * 8, 256, 0, stream>>>(soa, Marr, supC);
    k_sweep<<<8, 512, 0, stream>>>(soa, tgt, Marr, supC, counters, (float*)d_out);
}

// Round 10
// 155.953 us; speedup vs baseline: 1.1173x; 1.1173x over previous
//
#include <hip/hip_runtime.h>

namespace {
constexpr int NA    = 5;
constexpr int NCELL = 361;            // 19*19
constexpr int NBOX  = 1805;           // NA * NCELL
constexpr int SORTN = 2048;
constexpr int NT1   = 256;            // K1: 8 elems/thread register bitonic
constexpr int TMAX  = 50;
constexpr float CONF_T = 0.5f;
constexpr float NMS_T  = 0.45f;
constexpr float IOU_T  = 0.5f;
constexpr int NWMAX   = 32;
constexpr int ROWPAD  = 1856;         // padded col dim (mult of 64, >= 1805)
constexpr int SOA_STRIDE = ROWPAD;
constexpr int SOA_ARR    = 8 * SOA_STRIDE;
// ws layout (bytes)
constexpr size_t WS_COUNT = 0;        // 4 ints: prop, corr, total, done
constexpr size_t WS_M     = 64;       // 8 ints
constexpr size_t WS_SOA   = 256;      // 6 * SOA_ARR floats = 356,352 B
constexpr size_t WS_SUP   = 360448;   // 8 * 32 * ROWPAD * 8 = 3,801,088 B
}

__device__ __constant__ float d_anchw[NA] = {1.3221f, 3.19275f, 5.05587f, 9.47112f, 11.2364f};
__device__ __constant__ float d_anchh[NA] = {1.73145f, 4.00944f, 8.09892f, 4.84053f, 10.0071f};

// lgkm-only barrier: cross-wave state is all LDS; global prefetches stay in flight.
__device__ inline void barrier_lgkm() {
    __asm__ volatile("" ::: "memory");
    __builtin_amdgcn_s_waitcnt(0xC07F);   // vmcnt(63) expcnt(7) lgkmcnt(0)
    __builtin_amdgcn_s_barrier();
    __asm__ volatile("" ::: "memory");
}

// ---- K1: decode + register-blocked bitonic sort + sorted SoA to global ----
__global__ __launch_bounds__(NT1, 1) void k_decode_sort(
    const float* __restrict__ net, float* __restrict__ soa,
    int* __restrict__ Marr, int* __restrict__ counters)
{
    __shared__ unsigned long long skey[SORTN];   // 16 KB
    __shared__ float4 sbox[NBOX];                // 28.9 KB
    __shared__ int sM;
    const int b = blockIdx.x, tid = threadIdx.x;
    const float* op = net + (size_t)b * (NA * 25 * NCELL);
    if (tid == 0) sM = 0;
    if (b == 0 && tid < 4) counters[tid] = 0;    // replaces memset dispatch

    for (int n = tid; n < NBOX; n += NT1) {
        int a = n / NCELL;
        int r = n - a * NCELL;
        int y = r / 19;
        int x = r - y * 19;
        int base = a * 25 * NCELL + r;
        float t0 = op[base];
        float t1 = op[base + 1 * NCELL];
        float t2 = op[base + 2 * NCELL];
        float t3 = op[base + 3 * NCELL];
        float t4 = op[base + 4 * NCELL];
        float cx = (1.0f / (1.0f + expf(-t0)) + (float)x) / 19.0f;
        float cy = (1.0f / (1.0f + expf(-t1)) + (float)y) / 19.0f;
        float bw = expf(t2) * (d_anchw[a] / 19.0f);
        float bh = expf(t3) * (d_anchh[a] / 19.0f);
        float det = 1.0f / (1.0f + expf(-t4));
        sbox[n] = make_float4(cx, cy, bw, bh);
        skey[n] = ((unsigned long long)(~__float_as_uint(det)) << 32) | (unsigned)n;
    }
    for (int n = NBOX + tid; n < SORTN; n += NT1) skey[n] = ~0ull;
    __syncthreads();

    unsigned long long v[8];
    const int base8 = tid << 3;
    auto cas = [&](int x, int y, bool up) {
        unsigned long long a = v[x], c = v[y];
        if ((a > c) == up) { v[x] = c; v[y] = a; }
    };
    {
        #pragma unroll
        for (int p = 0; p < 8; ++p) v[p] = skey[base8 + p];
        cas(0,1,true); cas(2,3,false); cas(4,5,true); cas(6,7,false);
        cas(0,2,true); cas(1,3,true); cas(4,6,false); cas(5,7,false);
        cas(0,1,true); cas(2,3,true); cas(4,5,false); cas(6,7,false);
        bool u8 = ((base8 & 8) == 0);
        cas(0,4,u8); cas(1,5,u8); cas(2,6,u8); cas(3,7,u8);
        cas(0,2,u8); cas(1,3,u8); cas(4,6,u8); cas(5,7,u8);
        cas(0,1,u8); cas(2,3,u8); cas(4,5,u8); cas(6,7,u8);
        #pragma unroll
        for (int p = 0; p < 8; ++p) skey[base8 + p] = v[p];
    }
    __syncthreads();
    for (unsigned k = 16; k <= SORTN; k <<= 1) {
        for (unsigned j = k >> 1; j >= 8; j >>= 1) {
            #pragma unroll
            for (int c = 0; c < 4; ++c) {
                unsigned m = (tid << 2) + c;
                unsigned i = ((m & ~(j - 1)) << 1) | (m & (j - 1));
                unsigned p = i | j;
                bool up = ((i & k) == 0);
                unsigned long long a = skey[i], c2 = skey[p];
                if ((a > c2) == up) { skey[i] = c2; skey[p] = a; }
            }
            __syncthreads();
        }
        {
            #pragma unroll
            for (int p = 0; p < 8; ++p) v[p] = skey[base8 + p];
            bool up = ((base8 & k) == 0);
            cas(0,4,up); cas(1,5,up); cas(2,6,up); cas(3,7,up);
            cas(0,2,up); cas(1,3,up); cas(4,6,up); cas(5,7,up);
            cas(0,1,up); cas(2,3,up); cas(4,5,up); cas(6,7,up);
            #pragma unroll
            for (int p = 0; p < 8; ++p) skey[base8 + p] = v[p];
        }
        __syncthreads();
    }

    float* X1 = soa + 0 * SOA_ARR + b * SOA_STRIDE;
    float* Y1 = soa + 1 * SOA_ARR + b * SOA_STRIDE;
    float* X2 = soa + 2 * SOA_ARR + b * SOA_STRIDE;
    float* Y2 = soa + 3 * SOA_ARR + b * SOA_STRIDE;
    float* Wd = soa + 4 * SOA_ARR + b * SOA_STRIDE;
    float* Hd = soa + 5 * SOA_ARR + b * SOA_STRIDE;
    for (int p = tid; p < NBOX; p += NT1) {
        unsigned long long kk = skey[p];
        int n = (int)(unsigned)(kk & 0xffffffffull);
        float det = __uint_as_float(~(unsigned)(kk >> 32));
        float4 bx = sbox[n];
        X1[p] = bx.x - 0.5f * bx.z;
        Y1[p] = bx.y - 0.5f * bx.w;
        X2[p] = bx.x + 0.5f * bx.z;
        Y2[p] = bx.y + 0.5f * bx.w;
        Wd[p] = bx.z;
        Hd[p] = bx.w;
        if (det > CONF_T) {
            float dn = 0.0f;
            if (p + 1 < NBOX) dn = __uint_as_float(~(unsigned)(skey[p + 1] >> 32));
            if (!(dn > CONF_T)) sM = p + 1;      // unique boundary thread
        }
    }
    __syncthreads();
    if (tid == 0) Marr[b] = sM;
}

// ---- K2: COLUMN-oriented suppression words. One wave per sorted col j;
// lanes = rows i. supC[b][t][j] = ballot over rows i in tile t of
// "i suppresses j" (i<j, iou>thresh). XCD-swizzled (b = blk&7). ----
__global__ __launch_bounds__(256) void k_iou_colT(
    const float* __restrict__ soa, const int* __restrict__ Marr,
    unsigned long long* __restrict__ supC)
{
    const int blk  = blockIdx.x;
    const int b    = blk & 7;
    const int lane = threadIdx.x & 63;
    const int j    = (blk >> 3) * 4 + (threadIdx.x >> 6);
    const int M = Marr[b];
    if (j >= M) return;
    const float* X1 = soa + 0 * SOA_ARR + b * SOA_STRIDE;
    const float* Y1 = soa + 1 * SOA_ARR + b * SOA_STRIDE;
    const float* X2 = soa + 2 * SOA_ARR + b * SOA_STRIDE;
    const float* Y2 = soa + 3 * SOA_ARR + b * SOA_STRIDE;
    const float* Wd = soa + 4 * SOA_ARR + b * SOA_STRIDE;
    const float* Hd = soa + 5 * SOA_ARR + b * SOA_STRIDE;
    const float bx1 = X1[j], by1 = Y1[j], bx2 = X2[j], by2 = Y2[j];
    const float bw = Wd[j], bh = Hd[j], barea = bw * bh;
    const int jw = j >> 6;
    unsigned long long* outp = supC + (size_t)b * 32 * ROWPAD + j;
    for (int t = 0; t <= jw; ++t) {
        int i = (t << 6) + lane;                 // i <= 1855 < ROWPAD: in-bounds
        float ax1 = X1[i], ay1 = Y1[i], ax2 = X2[i], ay2 = Y2[i];
        float aw = Wd[i], ah = Hd[i];
        bool pred = false;
        if (i < j) {                             // i<j implies i<M
            float uw = fmaxf(ax2, bx2) - fminf(ax1, bx1);
            float uh = fmaxf(ay2, by2) - fminf(ay1, by1);
            float cw = aw + bw - uw;
            float ch = ah + bh - uh;
            if (cw > 0.0f && ch > 0.0f) {
                float ca = cw * ch;
                float ua = aw * ah + barea - ca;
                pred = ca > NMS_T * ua;          // iou > thresh
            }
        }
        unsigned long long m = __ballot(pred);
        if (lane == 0) outp[(size_t)t * ROWPAD] = m;
    }
}

// ---- K3: 8-wave, ONE barrier per tile. Wave 0: ballot sweep + in-register
// "urgent" next-word update. Waves 1-7: one-ballot lazy updates of owned
// future words using the previous tile's keep mask. All global loads are
// static-address depth-2 double-buffered. GT match from LDS SoA.
// Invariant: at iteration t, VC == V_t = (tile t colwords @ word t+1). ----
__global__ __launch_bounds__(512, 1) void k_sweep2(
    const float* __restrict__ soa, const float* __restrict__ tgt,
    const int* __restrict__ Marr, const unsigned long long* __restrict__ supC,
    int* __restrict__ counters, float* __restrict__ out)
{
    __shared__ float X1s[NBOX], Y1s[NBOX], X2s[NBOX], Y2s[NBOX];
    __shared__ float Wss[NBOX], Hss[NBOX];               // 43.3 KB
    __shared__ unsigned long long rmw[NWMAX], keepw[NWMAX];
    __shared__ int sNV, sCorr, sProp;
    const int b = blockIdx.x, tid = threadIdx.x;
    const int wv = tid >> 6, lane = tid & 63;
    const int M = Marr[b];
    const int nwa = (M + 63) >> 6;
    const unsigned long long* sb = supC + (size_t)b * 32 * ROWPAD;

    if (tid < NWMAX) { rmw[tid] = 0ull; keepw[tid] = 0ull; }
    if (tid == 0) { sCorr = 0; sProp = 0; }

    // stage sorted SoA into LDS (coalesced, 8 waves)
    {
        const float* X1 = soa + 0 * SOA_ARR + b * SOA_STRIDE;
        const float* Y1 = soa + 1 * SOA_ARR + b * SOA_STRIDE;
        const float* X2 = soa + 2 * SOA_ARR + b * SOA_STRIDE;
        const float* Y2 = soa + 3 * SOA_ARR + b * SOA_STRIDE;
        const float* Wd = soa + 4 * SOA_ARR + b * SOA_STRIDE;
        const float* Hd = soa + 5 * SOA_ARR + b * SOA_STRIDE;
        for (int p = tid; p < NBOX; p += 512) {
            X1s[p] = X1[p]; Y1s[p] = Y1[p];
            X2s[p] = X2[p]; Y2s[p] = Y2[p];
            Wss[p] = Wd[p]; Hss[p] = Hd[p];
        }
    }
    if (wv == 1) {       // GT count via ballot (first row with cx==0)
        float cxv = (lane < TMAX) ? tgt[b * 250 + lane * 5 + 1] : 0.0f;
        unsigned long long bm = __ballot(cxv != 0.0f);
        unsigned long long inv = (~bm) & ((1ull << TMAX) - 1);
        if (lane == 0) sNV = inv ? (__ffsll((long long)inv) - 1) : TMAX;
    }

    // lazy word ownership: wave v (1..7) owns words {v+1, v+8, v+15, v+22}
    int ow[4]; int now = 0;
    if (wv >= 1) {
        #pragma unroll
        for (int k = 0; k < 4; ++k) {
            int w = wv + 1 + 7 * k;
            if (w < nwa && w < NWMAX) ow[now++] = w;
        }
    }
    unsigned long long L[4];
    for (int i = 0; i < now; ++i)                 // tile-0 colwords (used at t=1)
        L[i] = sb[(size_t)(ow[i] << 6) + lane];

    // wave-0 depth-2 prefetch streams (static addresses)
    unsigned long long diagC = 0, diagN = 0, VC = 0, VN = 0, urgent = 0;
    if (wv == 0 && nwa > 0) {
        int t1 = (nwa > 1) ? 1 : 0;
        int t2 = (nwa > 2) ? 2 : t1;
        int w3 = (3 < NWMAX) ? 3 : (NWMAX - 1);
        diagC = sb[lane];                                          // diag tile 0
        diagN = sb[(size_t)t1 * ROWPAD + (t1 << 6) + lane];        // diag tile 1
        VC    = sb[(size_t)0 * ROWPAD + (t1 << 6) + lane];         // V_0: tile0 @ word1
        VN    = sb[(size_t)t1 * ROWPAD + ((t2 < NWMAX ? t2 : NWMAX - 1) << 6) + lane]; // V_1: tile1 @ word2
        (void)w3;
    }
    __syncthreads();   // staging + sNV + keepw/rmw init visible

    for (int t = 0; t < nwa; ++t) {
        if (wv == 0) {
            // ---- serial greedy sweep for tile t (ballot chain only) ----
            unsigned long long removed = rmw[t] | urgent;
            int rem = M - (t << 6);
            unsigned long long vm = (rem >= 64) ? ~0ull : ((1ull << rem) - 1ull);
            unsigned long long live = vm & ~removed;
            while (live) {
                int i = __ffsll((long long)live) - 1;              // uniform
                unsigned long long w = __ballot(((diagC >> i) & 1ull) != 0ull);
                removed |= w;
                live &= ~w;
                live &= ~(1ull << i);
            }
            unsigned long long kp = vm & ~removed;                 // uniform
            if (lane == 0) { keepw[t] = kp; sProp += __popcll(kp); }
            // urgent update of word t+1 (tile t's kept rows), in-register
            urgent = __ballot((VC & kp) != 0ull);
            // rotate depth-2 prefetch: VC <- V_{t+1}; VN <- V_{t+2}
            diagC = diagN; VC = VN;
            int tf = (t + 2 < nwa) ? (t + 2) : (nwa - 1);
            diagN = sb[(size_t)tf * ROWPAD + (tf << 6) + lane];
            int tg = (t + 2 < nwa) ? (t + 2) : (nwa - 1);          // FIX: was t+1
            int wg = (t + 3 < NWMAX) ? (t + 3) : (NWMAX - 1);      // FIX: was t+2
            VN = sb[(size_t)tg * ROWPAD + (wg << 6) + lane];       // V_{t+2}
        } else if (t >= 1) {
            // ---- lazy updates: tile t-1's keep mask into owned words >= t+1 ----
            unsigned long long km = keepw[t - 1];                  // LDS broadcast
            #pragma unroll
            for (int i = 0; i < 4; ++i) {
                if (i < now) {
                    int w = ow[i];
                    if (w >= t + 1) {
                        unsigned long long hit = __ballot((L[i] & km) != 0ull);
                        if (lane == 0 && hit) rmw[w] |= hit;       // word-exclusive
                        L[i] = sb[(size_t)t * ROWPAD + (w << 6) + lane]; // tile t
                    }
                }
            }
        }
        barrier_lgkm();   // keepw[t] + rmw updates visible next iteration
    }

    // ---- GT matching: 8 waves, branchless, LDS SoA ----
    const int nv = sNV;
    for (int t = wv; t < nv; t += 8) {
        const float* g = tgt + b * 250 + t * 5;
        float gcx = g[1], gcy = g[2], gw = g[3], gh = g[4];
        float gx1 = gcx - 0.5f * gw, gx2 = gcx + 0.5f * gw;
        float gy1 = gcy - 0.5f * gh, gy2 = gcy + 0.5f * gh;
        float garea = gw * gh;
        float best = 0.0f;
        for (int j0 = 0; j0 < M; j0 += 64) {
            int j = j0 + lane;
            bool ok = (j < M) && ((keepw[j0 >> 6] >> lane) & 1ull);
            int js = (j < NBOX) ? j : (NBOX - 1);
            float bw = Wss[js], bh = Hss[js];
            float uw = fmaxf(gx2, X2s[js]) - fminf(gx1, X1s[js]);
            float uh = fmaxf(gy2, Y2s[js]) - fminf(gy1, Y1s[js]);
            float cww = gw + bw - uw, chh = gh + bh - uh;
            float ca = (cww > 0.0f && chh > 0.0f) ? cww * chh : 0.0f;
            float ua = garea + bw * bh - ca;
            float iou = ca / ua;
            best = fmaxf(best, ok ? iou : 0.0f);
        }
        for (int d = 32; d > 0; d >>= 1) best = fmaxf(best, __shfl_down(best, d, 64));
        if (lane == 0 && best > IOU_T) atomicAdd(&sCorr, 1);
    }
    __syncthreads();

    if (tid == 0) {
        atomicAdd(counters + 0, sProp);
        atomicAdd(counters + 1, sCorr);
        atomicAdd(counters + 2, sNV);
        __threadfence();
        int done = atomicAdd(counters + 3, 1);
        if (done == 7) {
            float prop  = (float)atomicAdd(counters + 0, 0);
            float corr  = (float)atomicAdd(counters + 1, 0);
            float total = (float)atomicAdd(counters + 2, 0);
            float prec = corr / (prop + 1e-6f);
            float rec  = corr / (total + 1e-6f);
            float fs   = 2.0f * prec * rec / (prec + rec + 1e-6f);
            out[0] = total;
            out[1] = prop;
            out[2] = corr;
            out[3] = prec;
            out[4] = rec;
            out[5] = fs;
        }
    }
}

extern "C" void kernel_launch(void* const* d_in, const int* in_sizes, int n_in,
                              void* d_out, int out_size, void* d_ws, size_t ws_size,
                              hipStream_t stream) {
    const float* net = (const float*)d_in[0];   // [8,125,19,19] f32
    const float* tgt = (const float*)d_in[1];   // [8,250] f32
    char* ws = (char*)d_ws;
    int* counters = (int*)(ws + WS_COUNT);
    int* Marr     = (int*)(ws + WS_M);
    float* soa    = (float*)(ws + WS_SOA);
    unsigned long long* supC = (unsigned long long*)(ws + WS_SUP);

    k_decode_sort<<<8, NT1, 0, stream>>>(net, soa, Marr, counters);
    int colblocks = (NBOX + 3) / 4;              // 452
    k_iou_colT<<<colblocks * 8, 256, 0, stream>>>(soa, Marr, supC);
    k_sweep2<<<8, 512, 0, stream>>>(soa, tgt, Marr, supC, counters, (float*)d_out);
}

// Round 11
// 148.253 us; speedup vs baseline: 1.1753x; 1.0519x over previous
//
#include <hip/hip_runtime.h>

namespace {
constexpr int NA    = 5;
constexpr int NCELL = 361;            // 19*19
constexpr int NBOX  = 1805;           // NA * NCELL
constexpr int KPAD  = 2048;
constexpr int TMAX  = 50;
constexpr float CONF_T = 0.5f;
constexpr float NMS_T  = 0.45f;
constexpr float IOU_T  = 0.5f;
constexpr int NWMAX   = 32;
constexpr int TRI_T   = 15;           // LDS triangle capacity (tiles); nwa=15 for bench data
constexpr int TRI_SEG = TRI_T * (TRI_T + 1) / 2;   // 120 segments of 64 u64
constexpr int ROWPAD  = 1856;         // padded col dim (mult of 64, >= 1805)
constexpr int SOA_STRIDE = ROWPAD;
constexpr int SOA_ARR    = 8 * SOA_STRIDE;
// ws layout (bytes) — total usage stays within the 4.16 MB proven in R2-R10
constexpr size_t WS_COUNT = 0;        // 4 ints: prop, corr, total, done
constexpr size_t WS_M     = 64;       // 8 ints
constexpr size_t WS_SOA   = 256;      // sorted SoA: 6 * SOA_ARR floats = 356,352 B
constexpr size_t WS_SUP   = 360448;   // supC region: 8*32*ROWPAD*8 = 3,801,088 B
// temporaries INSIDE the supC region (K2 overwrites them after K1b is done):
constexpr size_t WS_UBOX  = WS_SUP;              // unsorted SoA, 356,352 B
constexpr size_t WS_KEY   = WS_SUP + (1u << 20); // keys, 8*2048*8 = 131,072 B
}

__device__ __constant__ float d_anchw[NA] = {1.3221f, 3.19275f, 5.05587f, 9.47112f, 11.2364f};
__device__ __constant__ float d_anchh[NA] = {1.73145f, 4.00944f, 8.09892f, 4.84053f, 10.0071f};

// uniform-index 64-bit readlane
__device__ inline unsigned long long rdlane64(unsigned long long v, int l) {
    unsigned lo = (unsigned)__builtin_amdgcn_readlane((int)(unsigned)(v & 0xffffffffull), l);
    unsigned hi = (unsigned)__builtin_amdgcn_readlane((int)(unsigned)(v >> 32), l);
    return ((unsigned long long)hi << 32) | lo;
}

// ---- K1a: decode -> unsorted SoA + sort keys + M count. 8 blocks. ----
__global__ __launch_bounds__(256, 1) void k_decode(
    const float* __restrict__ net, float* __restrict__ ubox,
    unsigned long long* __restrict__ keyg, int* __restrict__ Marr,
    int* __restrict__ counters)
{
    __shared__ int sM;
    const int b = blockIdx.x, tid = threadIdx.x, lane = tid & 63;
    const float* op = net + (size_t)b * (NA * 25 * NCELL);
    if (tid == 0) sM = 0;
    if (b == 0 && tid < 4) counters[tid] = 0;
    __syncthreads();

    int cnt = 0;
    for (int n = tid; n < NBOX; n += 256) {
        int a = n / NCELL;
        int r = n - a * NCELL;
        int y = r / 19;
        int x = r - y * 19;
        int base = a * 25 * NCELL + r;
        float t0 = op[base];
        float t1 = op[base + 1 * NCELL];
        float t2 = op[base + 2 * NCELL];
        float t3 = op[base + 3 * NCELL];
        float t4 = op[base + 4 * NCELL];
        float cx = (1.0f / (1.0f + expf(-t0)) + (float)x) / 19.0f;
        float cy = (1.0f / (1.0f + expf(-t1)) + (float)y) / 19.0f;
        float bw = expf(t2) * (d_anchw[a] / 19.0f);
        float bh = expf(t3) * (d_anchh[a] / 19.0f);
        float det = 1.0f / (1.0f + expf(-t4));
        // ascending key == stable argsort(-det)
        keyg[b * KPAD + n] = ((unsigned long long)(~__float_as_uint(det)) << 32) | (unsigned)n;
        ubox[0 * SOA_ARR + b * SOA_STRIDE + n] = cx - 0.5f * bw;
        ubox[1 * SOA_ARR + b * SOA_STRIDE + n] = cy - 0.5f * bh;
        ubox[2 * SOA_ARR + b * SOA_STRIDE + n] = cx + 0.5f * bw;
        ubox[3 * SOA_ARR + b * SOA_STRIDE + n] = cy + 0.5f * bh;
        ubox[4 * SOA_ARR + b * SOA_STRIDE + n] = bw;
        ubox[5 * SOA_ARR + b * SOA_STRIDE + n] = bh;
        cnt += (det > CONF_T) ? 1 : 0;
    }
    for (int n = NBOX + tid; n < KPAD; n += 256) keyg[b * KPAD + n] = ~0ull;
    for (int d = 32; d > 0; d >>= 1) cnt += __shfl_down(cnt, d, 64);
    if (lane == 0) atomicAdd(&sM, cnt);
    __syncthreads();
    if (tid == 0) Marr[b] = sM;    // M = conf>0.5 prefix length in sorted order
}

// ---- K1b: parallel rank sort. 113*8 blocks; each wave ranks 4 boxes via
// ballot-popcount over LDS-staged keys, then scatters the sorted SoA. ----
__global__ __launch_bounds__(256, 1) void k_rank(
    const unsigned long long* __restrict__ keyg, const float* __restrict__ ubox,
    float* __restrict__ soa)
{
    __shared__ unsigned long long lk[KPAD];      // 16 KB
    const int blk = blockIdx.x, tid = threadIdx.x;
    const int b = blk & 7, wv = tid >> 6, lane = tid & 63;
    for (int i = tid; i < KPAD; i += 256) lk[i] = keyg[b * KPAD + i];
    __syncthreads();

    const int base = (blk >> 3) * 16 + wv * 4;
    unsigned long long kp[4];
    int cnt[4] = {0, 0, 0, 0};
    #pragma unroll
    for (int x = 0; x < 4; ++x) {
        int p = base + x;
        kp[x] = (p < NBOX) ? lk[p] : 0ull;       // unused if p>=NBOX
    }
    for (int c = 0; c < KPAD / 64; ++c) {
        unsigned long long q = lk[(c << 6) + lane];
        #pragma unroll
        for (int x = 0; x < 4; ++x)
            cnt[x] += __popcll(__ballot(q < kp[x]));
    }
    #pragma unroll
    for (int x = 0; x < 4; ++x) {
        int p = base + x;
        if (p < NBOX && lane < 6) {
            float v = ubox[lane * SOA_ARR + b * SOA_STRIDE + p];
            soa[lane * SOA_ARR + b * SOA_STRIDE + cnt[x]] = v;   // rank = cnt
        }
    }
}

// ---- K2: COLUMN-oriented suppression words (verified R10). One wave per
// sorted col j; supC[b][t][j] = ballot over rows i in tile t of "i sup j". ----
__global__ __launch_bounds__(256) void k_iou_colT(
    const float* __restrict__ soa, const int* __restrict__ Marr,
    unsigned long long* __restrict__ supC)
{
    const int blk  = blockIdx.x;
    const int b    = blk & 7;
    const int lane = threadIdx.x & 63;
    const int j    = (blk >> 3) * 4 + (threadIdx.x >> 6);
    const int M = Marr[b];
    if (j >= M) return;
    const float* X1 = soa + 0 * SOA_ARR + b * SOA_STRIDE;
    const float* Y1 = soa + 1 * SOA_ARR + b * SOA_STRIDE;
    const float* X2 = soa + 2 * SOA_ARR + b * SOA_STRIDE;
    const float* Y2 = soa + 3 * SOA_ARR + b * SOA_STRIDE;
    const float* Wd = soa + 4 * SOA_ARR + b * SOA_STRIDE;
    const float* Hd = soa + 5 * SOA_ARR + b * SOA_STRIDE;
    const float bx1 = X1[j], by1 = Y1[j], bx2 = X2[j], by2 = Y2[j];
    const float bw = Wd[j], bh = Hd[j], barea = bw * bh;
    const int jw = j >> 6;
    unsigned long long* outp = supC + (size_t)b * 32 * ROWPAD + j;
    for (int t = 0; t <= jw; ++t) {
        int i = (t << 6) + lane;                 // i < ROWPAD: in-bounds
        float ax1 = X1[i], ay1 = Y1[i], ax2 = X2[i], ay2 = Y2[i];
        float aw = Wd[i], ah = Hd[i];
        bool pred = false;
        if (i < j) {                             // i<j implies i<M
            float uw = fmaxf(ax2, bx2) - fminf(ax1, bx1);
            float uh = fmaxf(ay2, by2) - fminf(ay1, by1);
            float cw = aw + bw - uw;
            float ch = ah + bh - uh;
            if (cw > 0.0f && ch > 0.0f) {
                float ca = cw * ch;
                float ua = aw * ah + barea - ca;
                pred = ca > NMS_T * ua;          // iou > thresh
            }
        }
        unsigned long long m = __ballot(pred);
        if (lane == 0) outp[(size_t)t * ROWPAD] = m;
    }
}

// ---- K3: stage supC triangle to LDS; ONE wave runs the whole greedy sweep
// (zero barriers, zero memory on the serial chain); 8 waves GT-match. ----
__global__ __launch_bounds__(512, 1) void k_sweep3(
    const float* __restrict__ soa, const float* __restrict__ tgt,
    const int* __restrict__ Marr, const unsigned long long* __restrict__ supC,
    int* __restrict__ counters, float* __restrict__ out)
{
    __shared__ unsigned long long tri[TRI_SEG * 64];   // 61,440 B
    __shared__ unsigned long long keepw[NWMAX];
    __shared__ int sNV, sCorr, sProp;
    const int b = blockIdx.x, tid = threadIdx.x;
    const int wv = tid >> 6, lane = tid & 63;
    const int M = Marr[b];
    const int nwa = (M + 63) >> 6;
    const unsigned long long* sb = supC + (size_t)b * 32 * ROWPAD;

    if (tid < NWMAX) keepw[tid] = 0ull;
    if (tid == 0) { sCorr = 0; sProp = 0; }

    // stage lower triangle (t<=w), seg = w*(w+1)/2 + t, coalesced 512B segments
    const int tcap = (nwa < TRI_T) ? nwa : TRI_T;
    const int ntri = tcap * (tcap + 1) / 2;
    for (int seg = wv; seg < ntri; seg += 8) {
        int w = 0;
        while ((w + 1) * (w + 2) / 2 <= seg) ++w;
        int t = seg - w * (w + 1) / 2;
        tri[seg * 64 + lane] = sb[(size_t)t * ROWPAD + (w << 6) + lane];
    }
    if (wv == 1) {       // GT count via ballot (first row with cx==0)
        float cxv = (lane < TMAX) ? tgt[b * 250 + lane * 5 + 1] : 0.0f;
        unsigned long long bm = __ballot(cxv != 0.0f);
        unsigned long long inv = (~bm) & ((1ull << TMAX) - 1);
        if (lane == 0) sNV = inv ? (__ffsll((long long)inv) - 1) : TMAX;
    }
    __syncthreads();

    // ---- wave 0: complete greedy NMS. lane w holds removed[w] (rmv) and
    // lane t holds keep[t] (kwv). All data LDS/register; ballots only. ----
    if (wv == 0 && nwa > 0) {
        unsigned long long rmv = 0, kwv = 0;
        int pcTot = 0;
        for (int t = 0; t < nwa; ++t) {
            unsigned long long cur = rdlane64(rmv, t);
            unsigned long long diag = (t < TRI_T)
                ? tri[(t * (t + 1) / 2 + t) * 64 + lane]
                : sb[(size_t)t * ROWPAD + (t << 6) + lane];
            int rem = M - (t << 6);
            unsigned long long vm = (rem >= 64) ? ~0ull : ((1ull << rem) - 1ull);
            unsigned long long live = vm & ~cur;
            while (live) {
                int i = __ffsll((long long)live) - 1;              // uniform
                unsigned long long w64 = __ballot(((diag >> i) & 1ull) != 0ull);
                cur |= w64;
                live &= ~w64;
                live &= ~(1ull << i);
            }
            unsigned long long kp = vm & ~cur;                     // uniform
            pcTot += __popcll(kp);
            kwv = (lane == t) ? kp : kwv;
            for (int w = t + 1; w < nwa; ++w) {
                unsigned long long cw = (w < TRI_T)
                    ? tri[(w * (w + 1) / 2 + t) * 64 + lane]
                    : sb[(size_t)t * ROWPAD + (w << 6) + lane];
                unsigned long long m = __ballot((cw & kp) != 0ull);
                rmv = (lane == w) ? (rmv | m) : rmv;
            }
        }
        if (lane < NWMAX) keepw[lane] = (lane < nwa) ? kwv : 0ull;
        if (lane == 0) sProp = pcTot;
    }
    __syncthreads();

    // ---- GT matching: 8 waves, branchless, sorted SoA from global ----
    const float* X1 = soa + 0 * SOA_ARR + b * SOA_STRIDE;
    const float* Y1 = soa + 1 * SOA_ARR + b * SOA_STRIDE;
    const float* X2 = soa + 2 * SOA_ARR + b * SOA_STRIDE;
    const float* Y2 = soa + 3 * SOA_ARR + b * SOA_STRIDE;
    const float* Wd = soa + 4 * SOA_ARR + b * SOA_STRIDE;
    const float* Hd = soa + 5 * SOA_ARR + b * SOA_STRIDE;
    const int nv = sNV;
    for (int t = wv; t < nv; t += 8) {
        const float* g = tgt + b * 250 + t * 5;
        float gcx = g[1], gcy = g[2], gw = g[3], gh = g[4];
        float gx1 = gcx - 0.5f * gw, gx2 = gcx + 0.5f * gw;
        float gy1 = gcy - 0.5f * gh, gy2 = gcy + 0.5f * gh;
        float garea = gw * gh;
        float best = 0.0f;
        for (int j0 = 0; j0 < M; j0 += 64) {
            int j = j0 + lane;
            bool ok = (j < M) && ((keepw[j0 >> 6] >> lane) & 1ull);
            int js = (j < NBOX) ? j : (NBOX - 1);
            float bw = Wd[js], bh = Hd[js];
            float uw = fmaxf(gx2, X2[js]) - fminf(gx1, X1[js]);
            float uh = fmaxf(gy2, Y2[js]) - fminf(gy1, Y1[js]);
            float cww = gw + bw - uw, chh = gh + bh - uh;
            float ca = (cww > 0.0f && chh > 0.0f) ? cww * chh : 0.0f;
            float ua = garea + bw * bh - ca;
            float iou = ca / ua;
            best = fmaxf(best, ok ? iou : 0.0f);
        }
        for (int d = 32; d > 0; d >>= 1) best = fmaxf(best, __shfl_down(best, d, 64));
        if (lane == 0 && best > IOU_T) atomicAdd(&sCorr, 1);
    }
    __syncthreads();

    if (tid == 0) {
        atomicAdd(counters + 0, sProp);
        atomicAdd(counters + 1, sCorr);
        atomicAdd(counters + 2, sNV);
        __threadfence();
        int done = atomicAdd(counters + 3, 1);
        if (done == 7) {
            float prop  = (float)atomicAdd(counters + 0, 0);
            float corr  = (float)atomicAdd(counters + 1, 0);
            float total = (float)atomicAdd(counters + 2, 0);
            float prec = corr / (prop + 1e-6f);
            float rec  = corr / (total + 1e-6f);
            float fs   = 2.0f * prec * rec / (prec + rec + 1e-6f);
            out[0] = total;
            out[1] = prop;
            out[2] = corr;
            out[3] = prec;
            out[4] = rec;
            out[5] = fs;
        }
    }
}

extern "C" void kernel_launch(void* const* d_in, const int* in_sizes, int n_in,
                              void* d_out, int out_size, void* d_ws, size_t ws_size,
                              hipStream_t stream) {
    const float* net = (const float*)d_in[0];   // [8,125,19,19] f32
    const float* tgt = (const float*)d_in[1];   // [8,250] f32
    char* ws = (char*)d_ws;
    int* counters = (int*)(ws + WS_COUNT);
    int* Marr     = (int*)(ws + WS_M);
    float* soa    = (float*)(ws + WS_SOA);
    float* ubox   = (float*)(ws + WS_UBOX);                       // temp (pre-K2)
    unsigned long long* keyg = (unsigned long long*)(ws + WS_KEY);// temp (pre-K2)
    unsigned long long* supC = (unsigned long long*)(ws + WS_SUP);

    k_decode<<<8, 256, 0, stream>>>(net, ubox, keyg, Marr, counters);
    k_rank<<<113 * 8, 256, 0, stream>>>(keyg, ubox, soa);
    k_iou_colT<<<452 * 8, 256, 0, stream>>>(soa, Marr, supC);
    k_sweep3<<<8, 512, 0, stream>>>(soa, tgt, Marr, supC, counters, (float*)d_out);
}